// Round 5
// baseline (463.741 us; speedup 1.0000x reference)
//
#include <hip/hip_runtime.h>

// MoE-INR fused megakernel, bf16 MFMA (gfx950). Round 5:
// 256 threads (4 waves), launch_bounds(256,2) -> no spills (r4 spilled 156MB
// scratch at VGPR=64). Explicit 2-deep register double-buffer prefetch of
// B (global/L2) and A (LDS) fragments in every MFMA K-loop: breaks the
// serial load->MFMA chain that r3/r4 counters showed (MfmaUtil pinned at 15%
// with occupancy 23% AND 44% => latency-chain-bound, not TLP-bound).

typedef short v8s __attribute__((ext_vector_type(8)));
typedef float v4f __attribute__((ext_vector_type(4)));

#define OMEGA_F 30.0f
#define AST 264   // LDS row stride in bf16 elements
#define N_CVT 8

__device__ __forceinline__ float bf2f(unsigned short h) {
  union { unsigned u; float f; } v; v.u = ((unsigned)h) << 16; return v.f;
}
__device__ __forceinline__ unsigned short f2bf(float f) {
  union { float f; unsigned u; } v; v.f = f;
  unsigned r = v.u + 0x7fffu + ((v.u >> 16) & 1u);  // RNE
  return (unsigned short)(r >> 16);
}

struct CvtArgs {
  const float* src[N_CVT];
  unsigned     off[N_CVT];
  unsigned     n[N_CVT];
};

__global__ void convert_kernel(CvtArgs a, unsigned short* __restrict__ dst) {
  const int tid = blockIdx.x * blockDim.x + threadIdx.x;
  const int stride = gridDim.x * blockDim.x;
  for (int k = 0; k < N_CVT; k++) {
    const unsigned n = a.n[k];
    const float* s = a.src[k];
    unsigned short* d = dst + a.off[k];
    for (unsigned i = tid; i < n; i += stride) d[i] = f2bf(s[i]);
  }
}

// ---------------- wave-level GEMM (4 waves, reg-double-buffered) ----------
// OUT[0:64, oc:oc+4*NPW*16] = act(A[0:64,0:K] @ W^T + bias)
// Wave tile: 64 rows x (NPW*16) cols. ACT: 0=sin(30z), 1=relu, 2=relu(z+skip)
template<int K, int NPW, int ACT>
__device__ __forceinline__ void wgemm(const unsigned short* A,
                                      unsigned short* OUT, int oc,
                                      const unsigned short* __restrict__ W,
                                      const float* __restrict__ bias,
                                      const unsigned short* skip) {
  const int lane = threadIdx.x & 63;
  const int wave = threadIdx.x >> 6;
  const int m15  = lane & 15;
  const int q    = lane >> 4;
  const int n0   = wave * (NPW * 16);
  constexpr int KI = K / 32;
  v4f acc[4][NPW];
#pragma unroll
  for (int i = 0; i < 4; i++)
#pragma unroll
    for (int j = 0; j < NPW; j++) acc[i][j] = (v4f){0.f, 0.f, 0.f, 0.f};

  v8s a[2][4], b[2][NPW];
  // prologue: fragments for k0 = 0
#pragma unroll
  for (int ct = 0; ct < NPW; ct++)
    b[0][ct] = *(const v8s*)(W + (size_t)(n0 + ct * 16 + m15) * K + q * 8);
#pragma unroll
  for (int rt = 0; rt < 4; rt++)
    a[0][rt] = *(const v8s*)(A + (rt * 16 + m15) * AST + q * 8);

#pragma unroll
  for (int k0 = 0; k0 < KI; ++k0) {
    const int cur = k0 & 1, nxt = cur ^ 1;
    if (k0 + 1 < KI) {  // issue next-step loads before this step's MFMAs
#pragma unroll
      for (int ct = 0; ct < NPW; ct++)
        b[nxt][ct] = *(const v8s*)(W + (size_t)(n0 + ct * 16 + m15) * K +
                                   (k0 + 1) * 32 + q * 8);
#pragma unroll
      for (int rt = 0; rt < 4; rt++)
        a[nxt][rt] = *(const v8s*)(A + (rt * 16 + m15) * AST +
                                   (k0 + 1) * 32 + q * 8);
    }
#pragma unroll
    for (int rt = 0; rt < 4; rt++)
#pragma unroll
      for (int ct = 0; ct < NPW; ct++)
        acc[rt][ct] = __builtin_amdgcn_mfma_f32_16x16x32_bf16(a[cur][rt], b[cur][ct], acc[rt][ct], 0, 0, 0);
  }

#pragma unroll
  for (int ct = 0; ct < NPW; ct++) {
    const int col = n0 + ct * 16 + m15;
    const float bv = bias[col];
#pragma unroll
    for (int rt = 0; rt < 4; rt++) {
#pragma unroll
      for (int r = 0; r < 4; r++) {
        const int row = rt * 16 + q * 4 + r;
        float z = acc[rt][ct][r] + bv;
        float o;
        if (ACT == 0)      o = __sinf(OMEGA_F * z);
        else if (ACT == 1) o = fmaxf(z, 0.f);
        else { z += bf2f(skip[row * AST + col]); o = fmaxf(z, 0.f); }
        OUT[row * AST + oc + col] = f2bf(o);
      }
    }
  }
}

// Expert layer 2 fused with final 256->1 dot; 4 waves, 64 cols/wave.
// Writes per-wave partials to predw[wave][row] (no LDS atomics).
__device__ __forceinline__ void wexpert2(const unsigned short* A,
                                         const unsigned short* __restrict__ W,
                                         const float* __restrict__ bias,
                                         const float* __restrict__ wfin,
                                         float* predw /* [4][64] */) {
  const int lane = threadIdx.x & 63;
  const int wave = threadIdx.x >> 6;
  const int m15  = lane & 15;
  const int q    = lane >> 4;
  const int n0   = wave * 64;
  v4f acc[4][4];
#pragma unroll
  for (int i = 0; i < 4; i++)
#pragma unroll
    for (int j = 0; j < 4; j++) acc[i][j] = (v4f){0.f, 0.f, 0.f, 0.f};

  v8s a[2][4], b[2][4];
#pragma unroll
  for (int ct = 0; ct < 4; ct++)
    b[0][ct] = *(const v8s*)(W + (size_t)(n0 + ct * 16 + m15) * 256 + q * 8);
#pragma unroll
  for (int rt = 0; rt < 4; rt++)
    a[0][rt] = *(const v8s*)(A + (rt * 16 + m15) * AST + q * 8);

#pragma unroll
  for (int k0 = 0; k0 < 8; ++k0) {
    const int cur = k0 & 1, nxt = cur ^ 1;
    if (k0 + 1 < 8) {
#pragma unroll
      for (int ct = 0; ct < 4; ct++)
        b[nxt][ct] = *(const v8s*)(W + (size_t)(n0 + ct * 16 + m15) * 256 +
                                   (k0 + 1) * 32 + q * 8);
#pragma unroll
      for (int rt = 0; rt < 4; rt++)
        a[nxt][rt] = *(const v8s*)(A + (rt * 16 + m15) * AST +
                                   (k0 + 1) * 32 + q * 8);
    }
#pragma unroll
    for (int rt = 0; rt < 4; rt++)
#pragma unroll
      for (int ct = 0; ct < 4; ct++)
        acc[rt][ct] = __builtin_amdgcn_mfma_f32_16x16x32_bf16(a[cur][rt], b[cur][ct], acc[rt][ct], 0, 0, 0);
  }

  float p[4][4];
#pragma unroll
  for (int rt = 0; rt < 4; rt++)
#pragma unroll
    for (int r = 0; r < 4; r++) p[rt][r] = 0.f;
#pragma unroll
  for (int ct = 0; ct < 4; ct++) {
    const int col = n0 + ct * 16 + m15;
    const float bv = bias[col];
    const float wv = wfin[col];
#pragma unroll
    for (int rt = 0; rt < 4; rt++)
#pragma unroll
      for (int r = 0; r < 4; r++) {
        float s = __sinf(OMEGA_F * (acc[rt][ct][r] + bv));
        p[rt][r] += s * wv;
      }
  }
#pragma unroll
  for (int rt = 0; rt < 4; rt++)
#pragma unroll
    for (int r = 0; r < 4; r++) {
      float v = p[rt][r];
      v += __shfl_xor(v, 1);
      v += __shfl_xor(v, 2);
      v += __shfl_xor(v, 4);
      v += __shfl_xor(v, 8);
      if (m15 == 0) predw[wave * 64 + rt * 16 + q * 4 + r] = v;
    }
}

__global__ __launch_bounds__(256, 2) void moe_inr_kernel(
    const float* __restrict__ x,
    const unsigned short* __restrict__ es1w, const float* __restrict__ es1b,
    const unsigned short* __restrict__ es2w, const float* __restrict__ es2b,
    const unsigned short* __restrict__ rf1w, const float* __restrict__ rf1b,
    const unsigned short* __restrict__ rf2w, const float* __restrict__ rf2b,
    const unsigned short* __restrict__ rf3w, const float* __restrict__ rf3b,
    const float* __restrict__ ps1w,          const float* __restrict__ ps1b,
    const unsigned short* __restrict__ ps2w, const float* __restrict__ ps2b,
    const float* __restrict__ gw,            const float* __restrict__ gb,
    const unsigned short* __restrict__ xs1w, const float* __restrict__ xs1b,
    const unsigned short* __restrict__ xs2w, const float* __restrict__ xs2b,
    const float* __restrict__ xfw,           const float* __restrict__ xfb,
    float* __restrict__ out) {
  __shared__ __align__(16) unsigned short P[64 * AST];
  __shared__ __align__(16) unsigned short Q[64 * AST];
  __shared__ float probs[64 * 8];
  __shared__ float yacc[64];
  __shared__ float predw[4 * 64];

  const int t  = threadIdx.x;
  const int r0 = blockIdx.x * 64;

  // Stage 0: positional encoding in f32 -> P cols [0,64)
  {
    const int row = t & 63, c = t >> 6;
    const float xv = x[(r0 + row) * 4 + c];
    const float PIf = 3.14159265358979f;
#pragma unroll
    for (int j = 0; j < 8; j++) {
      float ang = xv * (PIf * (float)(1 << j));
      P[row * AST + c * 16 + j]     = f2bf(__sinf(ang));
      P[row * AST + c * 16 + 8 + j] = f2bf(__cosf(ang));
    }
    if (t < 64) yacc[t] = 0.f;
  }
  __syncthreads();
  wgemm<64, 2, 0>(P, P, 64, es1w, es1b, nullptr);        // h1 -> P[64,192)
  __syncthreads();
  wgemm<128, 4, 0>(P + 64, Q, 0, es2w, es2b, nullptr);   // h  -> Q[0,256)
  __syncthreads();
  wgemm<256, 2, 1>(Q, P, 0, rf1w, rf1b, nullptr);        // r1 -> P[0,128)
  __syncthreads();
  wgemm<128, 2, 1>(P, P, 128, rf2w, rf2b, nullptr);      // r2 -> P[128,256)
  __syncthreads();
  wgemm<128, 4, 2>(P + 128, Q, 0, rf3w, rf3b, Q);        // enc_feat -> Q (skip=h)
  __syncthreads();
  // pol_s1 (K=4) in f32: pf1 -> P[0,128)
  {
    const int row = t & 63, g = t >> 6;
    const float xv0 = x[(r0 + row) * 4 + 0];
    const float xv1 = x[(r0 + row) * 4 + 1];
    const float xv2 = x[(r0 + row) * 4 + 2];
    const float xv3 = x[(r0 + row) * 4 + 3];
    for (int i = 0; i < 32; i++) {
      int o = g * 32 + i;
      float z = xv0 * ps1w[o * 4 + 0] + xv1 * ps1w[o * 4 + 1] +
                xv2 * ps1w[o * 4 + 2] + xv3 * ps1w[o * 4 + 3] + ps1b[o];
      P[row * AST + o] = f2bf(__sinf(OMEGA_F * z));
    }
  }
  __syncthreads();
  wgemm<128, 2, 0>(P, P, 128, ps2w, ps2b, nullptr);      // pf -> P[128,256)
  __syncthreads();
  // gate (f32 weights): 4 partial-threads per row (96 k each)
  {
    const int row = t >> 2, pp = t & 3;
    float lg[7];
#pragma unroll
    for (int j = 0; j < 7; j++) {
      float s = 0.f;
      for (int kk = pp * 96; kk < pp * 96 + 96; ++kk) {
        float v = (kk < 256) ? bf2f(Q[row * AST + kk])
                             : bf2f(P[row * AST + 128 + (kk - 256)]);
        s += v * gw[j * 384 + kk];
      }
      s += __shfl_xor(s, 1);
      s += __shfl_xor(s, 2);
      lg[j] = s;
    }
    if (pp == 0) {
#pragma unroll
      for (int j = 0; j < 7; j++) probs[row * 8 + j] = lg[j] + gb[j];
    }
  }
  __syncthreads();
  if (t < 64) {  // softmax over 7
    float m = probs[t * 8];
#pragma unroll
    for (int j = 1; j < 7; j++) m = fmaxf(m, probs[t * 8 + j]);
    float s = 0.f, e[7];
#pragma unroll
    for (int j = 0; j < 7; j++) { e[j] = __expf(probs[t * 8 + j] - m); s += e[j]; }
    float inv = 1.f / s;
#pragma unroll
    for (int j = 0; j < 7; j++) probs[t * 8 + j] = e[j] * inv;
  }
  // experts: enc_feat stays in Q; e1 -> P; e2+final fused in registers
  for (int ex = 0; ex < 7; ++ex) {
    __syncthreads();
    wgemm<256, 4, 0>(Q, P, 0, xs1w + ex * 65536, xs1b + ex * 256, nullptr);
    __syncthreads();
    wexpert2(P, xs2w + ex * 65536, xs2b + ex * 256, xfw + ex * 256, predw);
    __syncthreads();
    if (t < 64)
      yacc[t] += (predw[t] + predw[64 + t] + predw[128 + t] + predw[192 + t] +
                  xfb[ex]) * probs[t * 8 + ex];
  }
  __syncthreads();
  if (t < 64) out[r0 + t] = yacc[t];
}

extern "C" void kernel_launch(void* const* d_in, const int* in_sizes, int n_in,
                              void* d_out, int out_size, void* d_ws, size_t ws_size,
                              hipStream_t stream) {
  (void)out_size; (void)n_in; (void)ws_size;
  const int idx[N_CVT] = {1, 3, 5, 7, 9, 13, 17, 19};
  unsigned off[N_CVT], cur = 0;
  CvtArgs a;
  for (int i = 0; i < N_CVT; i++) {
    off[i] = cur;
    a.src[i] = (const float*)d_in[idx[i]];
    a.off[i] = cur;
    a.n[i]   = (unsigned)in_sizes[idx[i]];
    cur += ((unsigned)in_sizes[idx[i]] + 7u) & ~7u;  // 16B-align each array
  }
  unsigned short* dst = (unsigned short*)d_ws;
  hipLaunchKernelGGL(convert_kernel, dim3(256), dim3(256), 0, stream, a, dst);
  hipLaunchKernelGGL(moe_inr_kernel, dim3(65536 / 64), dim3(256), 0, stream,
      (const float*)d_in[0],
      dst + off[0], (const float*)d_in[2],
      dst + off[1], (const float*)d_in[4],
      dst + off[2], (const float*)d_in[6],
      dst + off[3], (const float*)d_in[8],
      dst + off[4], (const float*)d_in[10],
      (const float*)d_in[11], (const float*)d_in[12],
      dst + off[5], (const float*)d_in[14],
      (const float*)d_in[15], (const float*)d_in[16],
      dst + off[6], (const float*)d_in[18],
      dst + off[7], (const float*)d_in[20],
      (const float*)d_in[21], (const float*)d_in[22],
      (float*)d_out);
}